// Round 4
// baseline (108.558 us; speedup 1.0000x reference)
//
#include <hip/hip_runtime.h>
#include <math.h>

#define HGT 1024
#define WID 2048

// f64 tables in ws: [0,HGT) sinT | [HGT,2H) cosT | [2H,2H+W) sinP | [2H+W,2H+2W) cosP
#define WS_DOUBLES (2 * HGT + 2 * WID)   // 6144 doubles = 48 KiB

__global__ __launch_bounds__(256) void fill_tables_k(double* __restrict__ ws) {
    int i = blockIdx.x * 256 + threadIdx.x;
    if (i < HGT) {
        // gx = -1 + i*2^-9 : exact in f64
        double gx = -1.0 + (2.0 / HGT) * (double)i;
        // numpy: theta = gx*(pi/2) + pi/2 (mul then add, two roundings, no FMA)
        double th = __dadd_rn(__dmul_rn(gx, M_PI / 2), M_PI / 2);
        ws[i]       = sin(th);
        ws[HGT + i] = cos(th);
    }
    if (i < WID) {
        double gy = -1.0 + (2.0 / WID) * (double)i;
        double ph = __dmul_rn(gy, M_PI);
        ws[2 * HGT + i]       = sin(ph);
        ws[2 * HGT + WID + i] = cos(ph);
    }
}

// Bit-faithful f32 replication of the numpy reference downstream of the grid.
// Sign-critical: py must match np.einsum's stepwise-f32 rounding bit-for-bit.
__device__ __forceinline__ void px_f32_chain(
    float gx32, float gy32, float zc, float d,
    const float* __restrict__ Tb, float* __restrict__ res2)
{
    // xyz = grid32 * depth  (elementwise f32 mul, correctly rounded)
    float xd = __fmul_rn(gx32, d);
    float yd = __fmul_rn(gy32, d);
    float zd = __fmul_rn(zc,   d);

    // einsum 'k,kj->j': sequential k-ascending, f32 mul+add, NO FMA.
    // acc = xd*T0j; acc += yd*T1j; acc += zd*T2j; acc += 1.0*T3j
    float px = __fadd_rn(__fadd_rn(__fadd_rn(
                   __fmul_rn(xd, Tb[0]), __fmul_rn(yd, Tb[4])),
                   __fmul_rn(zd, Tb[8])), Tb[12]);
    float py = __fadd_rn(__fadd_rn(__fadd_rn(
                   __fmul_rn(xd, Tb[1]), __fmul_rn(yd, Tb[5])),
                   __fmul_rn(zd, Tb[9])), Tb[13]);
    float pz = __fadd_rn(__fadd_rn(__fadd_rn(
                   __fmul_rn(xd, Tb[2]), __fmul_rn(yd, Tb[6])),
                   __fmul_rn(zd, Tb[10])), Tb[14]);

    // r = sqrt((x*x + y*y) + z*z) + 1e-4, all f32 like numpy
    float xx = __fmul_rn(px, px);
    float yy = __fmul_rn(py, py);
    float zz = __fmul_rn(pz, pz);
    float s2 = __fadd_rn(__fadd_rn(xx, yy), zz);
    float r  = __fadd_rn(__fsqrt_rn(s2), 1e-4f);

    // theta = arccos(z/r) / f32(pi/2) - 1 ; phi = atan2(y,x) / f32(pi)
    float u  = __fdiv_rn(pz, r);
    float to = __fsub_rn(__fdiv_rn(acosf(u), 1.57079637f), 1.0f);
    float po = __fdiv_rn(atan2f(py, px), 3.14159274f);

    res2[0] = po;   // phi
    res2[1] = to;   // theta
}

// Main kernel: 4 pixels per thread along w.
__global__ __launch_bounds__(256) void depth3d_k(
    const float* __restrict__ depth, const float* __restrict__ trans,
    const double* __restrict__ ws, float* __restrict__ out)
{
    int t   = blockIdx.x * 256 + threadIdx.x;   // 4-pixel group id
    int pix = t << 2;
    int b   = pix >> 21;                        // / (HGT*WID)
    int rem = pix & ((1 << 21) - 1);
    int h   = rem >> 11;                        // / WID
    int w   = rem & (WID - 1);                  // multiple of 4

    float4 d4 = *reinterpret_cast<const float4*>(depth + pix);

    double st = ws[h];
    double ct = ws[HGT + h];
    const double4 sp = *reinterpret_cast<const double4*>(ws + 2 * HGT + w);
    const double4 cp = *reinterpret_cast<const double4*>(ws + 2 * HGT + WID + w);

    const float* Tb = trans + b * 16;           // T[b][k][j], row-major
    float T[15];
#pragma unroll
    for (int k = 0; k < 15; ++k) T[k] = Tb[k];

    // grid z: f32 cast of f64 cos(theta) — replicates _GRID3D bitwise
    float zc = (float)ct;

    double spv[4] = {sp.x, sp.y, sp.z, sp.w};
    double cpv[4] = {cp.x, cp.y, cp.z, cp.w};
    float  dv[4]  = {d4.x, d4.y, d4.z, d4.w};
    float  res[8];

#pragma unroll
    for (int i = 0; i < 4; ++i) {
        // grid x,y: f64 product then single f32 cast — exactly numpy's
        // sin(theta)*cos(phi) in f64 then .astype(float32)
        float gx32 = (float)__dmul_rn(st, cpv[i]);
        float gy32 = (float)__dmul_rn(st, spv[i]);
        px_f32_chain(gx32, gy32, zc, dv[i], T, &res[2 * i]);
    }

    float4* o = reinterpret_cast<float4*>(out + (size_t)pix * 2);
    o[0] = make_float4(res[0], res[1], res[2], res[3]);
    o[1] = make_float4(res[4], res[5], res[6], res[7]);
}

// Fallback if ws too small: inline f64 trig, same f32 chain.
__global__ __launch_bounds__(256) void depth3d_inline_k(
    const float* __restrict__ depth, const float* __restrict__ trans,
    float* __restrict__ out)
{
    int t   = blockIdx.x * 256 + threadIdx.x;
    int pix = t << 2;
    int b   = pix >> 21;
    int rem = pix & ((1 << 21) - 1);
    int h   = rem >> 11;
    int w   = rem & (WID - 1);

    float4 d4 = *reinterpret_cast<const float4*>(depth + pix);

    double gx = -1.0 + (2.0 / HGT) * (double)h;
    double th = __dadd_rn(__dmul_rn(gx, M_PI / 2), M_PI / 2);
    double st = sin(th), ct = cos(th);

    double spv[4], cpv[4];
#pragma unroll
    for (int i = 0; i < 4; ++i) {
        double gy = -1.0 + (2.0 / WID) * (double)(w + i);
        double ph = __dmul_rn(gy, M_PI);
        spv[i] = sin(ph);
        cpv[i] = cos(ph);
    }

    const float* Tb = trans + b * 16;
    float T[15];
#pragma unroll
    for (int k = 0; k < 15; ++k) T[k] = Tb[k];

    float zc = (float)ct;
    float dv[4] = {d4.x, d4.y, d4.z, d4.w};
    float res[8];

#pragma unroll
    for (int i = 0; i < 4; ++i) {
        float gx32 = (float)__dmul_rn(st, cpv[i]);
        float gy32 = (float)__dmul_rn(st, spv[i]);
        px_f32_chain(gx32, gy32, zc, dv[i], T, &res[2 * i]);
    }

    float4* o = reinterpret_cast<float4*>(out + (size_t)pix * 2);
    o[0] = make_float4(res[0], res[1], res[2], res[3]);
    o[1] = make_float4(res[4], res[5], res[6], res[7]);
}

extern "C" void kernel_launch(void* const* d_in, const int* in_sizes, int n_in,
                              void* d_out, int out_size, void* d_ws, size_t ws_size,
                              hipStream_t stream)
{
    const float* depth = (const float*)d_in[0];
    const float* trans = (const float*)d_in[1];
    float*       out   = (float*)d_out;
    double*      ws    = (double*)d_ws;

    const int total_pix = 4 * HGT * WID;   // 8,388,608
    const int threads   = total_pix / 4;   // 2,097,152
    const int blocks    = threads / 256;   // 8192

    if (ws_size >= WS_DOUBLES * sizeof(double)) {
        // ws re-poisoned before every timed launch -> refill unconditionally
        fill_tables_k<<<(WID + 255) / 256, 256, 0, stream>>>(ws);
        depth3d_k<<<blocks, 256, 0, stream>>>(depth, trans, ws, out);
    } else {
        depth3d_inline_k<<<blocks, 256, 0, stream>>>(depth, trans, out);
    }
}

// Round 7
// 103.046 us; speedup vs baseline: 1.0535x; 1.0535x over previous
//
#include <hip/hip_runtime.h>
#include <math.h>

#define HGT 1024
#define WID 2048

// f64 tables in ws: [0,HGT) sinT | [HGT,2H) cosT | [2H,2H+W) sinP | [2H+W,2H+2W) cosP
#define WS_DOUBLES (2 * HGT + 2 * WID)   // 6144 doubles = 48 KiB

__global__ __launch_bounds__(256) void fill_tables_k(double* __restrict__ ws) {
    int i = blockIdx.x * 256 + threadIdx.x;
    if (i < HGT) {
        double gx = -1.0 + (2.0 / HGT) * (double)i;          // exact
        double th = __dadd_rn(__dmul_rn(gx, M_PI / 2), M_PI / 2); // numpy op order
        ws[i]       = sin(th);
        ws[HGT + i] = cos(th);
    }
    if (i < WID) {
        double gy = -1.0 + (2.0 / WID) * (double)i;
        double ph = __dmul_rn(gy, M_PI);
        ws[2 * HGT + i]       = sin(ph);
        ws[2 * HGT + WID + i] = cos(ph);
    }
}

// Fast approx acos, Cephes asinf core. |err| ~1e-7. Input |u| < 1 guaranteed.
__device__ __forceinline__ float acos_fast(float u) {
    float au  = fabsf(u);
    bool  big = au > 0.5f;
    float z   = big ? 0.5f * (1.0f - au) : au * au;
    float x   = big ? sqrtf(z) : au;
    float p   = fmaf(fmaf(fmaf(fmaf(4.2163199048e-2f, z, 2.4181311049e-2f),
                               z, 4.5470025998e-2f),
                          z, 7.4953002686e-2f),
                     z, 1.6666752422e-1f);
    p = fmaf(z * x, p, x);                       // asin-core(x)
    float ac = big ? 2.0f * p : (1.57079637f - p);   // acos(|u|)
    return (u < 0.0f) ? (3.14159274f - ac) : ac;
}

// Fast atan2 with IEEE-correct quadrant/sign semantics (cut side decided ONLY
// by py's sign bit, which is bit-exact vs the np reference). |err| ~1e-7.
__device__ __forceinline__ float atan2_fast(float y, float x) {
    float ax = fabsf(x), ay = fabsf(y);
    float mn = fminf(ax, ay), mx = fmaxf(ax, ay);
    // reduction: t>tan(pi/8) -> (t-1)/(t+1) == (mn-mx)/(mn+mx); one rcp total
    bool  red = mn > 0.41421356f * mx;
    float num = red ? (mn - mx) : mn;
    float den = red ? (mn + mx) : mx;
    den = (mx == 0.0f) ? 1.0f : den;             // atan2(0,0) -> 0 core
    float t  = num * __builtin_amdgcn_rcpf(den); // |t| <= 0.4142
    float z  = t * t;
    float pq = fmaf(fmaf(fmaf(8.05374449538e-2f, z, -1.38776856032e-1f),
                         z, 1.99777106478e-1f),
                    z, -3.33329491539e-1f);
    float a  = fmaf(t * z, pq, t);
    if (red) a += 0.78539816f;                   // + pi/4
    if (ay > ax) a = 1.57079637f - a;            // first-octant unfold
    if (__float_as_uint(x) >> 31) a = 3.14159274f - a;  // x negative (incl -0)
    return copysignf(a, y);
}

// Bit-faithful f32 einsum chain (sign-critical), fast finish.
__device__ __forceinline__ void px_f32_chain(
    float gx32, float gy32, float zc, float d,
    const float* __restrict__ Tb, float* __restrict__ res2)
{
    float xd = __fmul_rn(gx32, d);
    float yd = __fmul_rn(gy32, d);
    float zd = __fmul_rn(zc,   d);

    // einsum 'k,kj->j': sequential k-ascending, f32 mul+add, NO FMA (bit-exact)
    float px = __fadd_rn(__fadd_rn(__fadd_rn(
                   __fmul_rn(xd, Tb[0]), __fmul_rn(yd, Tb[4])),
                   __fmul_rn(zd, Tb[8])), Tb[12]);
    float py = __fadd_rn(__fadd_rn(__fadd_rn(
                   __fmul_rn(xd, Tb[1]), __fmul_rn(yd, Tb[5])),
                   __fmul_rn(zd, Tb[9])), Tb[13]);
    float pz = __fadd_rn(__fadd_rn(__fadd_rn(
                   __fmul_rn(xd, Tb[2]), __fmul_rn(yd, Tb[6])),
                   __fmul_rn(zd, Tb[10])), Tb[14]);

    // r = sqrt((x*x + y*y) + z*z) + 1e-4  (bit-exact: feeds u's amplification)
    float s2 = __fadd_rn(__fadd_rn(__fmul_rn(px, px), __fmul_rn(py, py)),
                         __fmul_rn(pz, pz));
    float r  = __fadd_rn(__fsqrt_rn(s2), 1e-4f);

    // u = z/r via fast rcp: 2 ulp, amplified <= ~250x by acos slope -> <=3e-5
    float u  = pz * __builtin_amdgcn_rcpf(r);
    float to = fmaf(acos_fast(u), 0.63661977f, -1.0f);   // /(pi/2) - 1
    float po = atan2_fast(py, px) * 0.31830988f;         // /pi

    res2[0] = po;   // phi
    res2[1] = to;   // theta
}

// Main kernel: 4 pixels per thread along w. h is uniform per block (1024-px
// blocks never cross a 2048-px row) -> st/ct scalarize.
__global__ __launch_bounds__(256) void depth3d_k(
    const float* __restrict__ depth, const float* __restrict__ trans,
    const double* __restrict__ ws, float* __restrict__ out)
{
    int t   = blockIdx.x * 256 + threadIdx.x;
    int pix = t << 2;
    int b   = pix >> 21;
    int rem = pix & ((1 << 21) - 1);
    int h   = rem >> 11;
    int w   = rem & (WID - 1);

    float4 d4 = *reinterpret_cast<const float4*>(depth + pix);

    double st = ws[h];
    double ct = ws[HGT + h];
    const double4 sp = *reinterpret_cast<const double4*>(ws + 2 * HGT + w);
    const double4 cp = *reinterpret_cast<const double4*>(ws + 2 * HGT + WID + w);

    const float* Tb = trans + b * 16;
    float T[15];
#pragma unroll
    for (int k = 0; k < 15; ++k) T[k] = Tb[k];

    float zc = (float)ct;                         // f32 cast of f64 cos(theta)

    double spv[4] = {sp.x, sp.y, sp.z, sp.w};
    double cpv[4] = {cp.x, cp.y, cp.z, cp.w};
    float  dv[4]  = {d4.x, d4.y, d4.z, d4.w};
    float  res[8];

#pragma unroll
    for (int i = 0; i < 4; ++i) {
        // grid x,y: f64 product then single f32 cast — bitwise _GRID3D
        float gx32 = (float)__dmul_rn(st, cpv[i]);
        float gy32 = (float)__dmul_rn(st, spv[i]);
        px_f32_chain(gx32, gy32, zc, dv[i], T, &res[2 * i]);
    }

    float4* o = reinterpret_cast<float4*>(out + (size_t)pix * 2);
    o[0] = make_float4(res[0], res[1], res[2], res[3]);
    o[1] = make_float4(res[4], res[5], res[6], res[7]);
}

// Fallback if ws too small: inline f64 trig, same chain.
__global__ __launch_bounds__(256) void depth3d_inline_k(
    const float* __restrict__ depth, const float* __restrict__ trans,
    float* __restrict__ out)
{
    int t   = blockIdx.x * 256 + threadIdx.x;
    int pix = t << 2;
    int b   = pix >> 21;
    int rem = pix & ((1 << 21) - 1);
    int h   = rem >> 11;
    int w   = rem & (WID - 1);

    float4 d4 = *reinterpret_cast<const float4*>(depth + pix);

    double gx = -1.0 + (2.0 / HGT) * (double)h;
    double th = __dadd_rn(__dmul_rn(gx, M_PI / 2), M_PI / 2);
    double st = sin(th), ct = cos(th);

    double spv[4], cpv[4];
#pragma unroll
    for (int i = 0; i < 4; ++i) {
        double gy = -1.0 + (2.0 / WID) * (double)(w + i);
        double ph = __dmul_rn(gy, M_PI);
        spv[i] = sin(ph);
        cpv[i] = cos(ph);
    }

    const float* Tb = trans + b * 16;
    float T[15];
#pragma unroll
    for (int k = 0; k < 15; ++k) T[k] = Tb[k];

    float zc = (float)ct;
    float dv[4] = {d4.x, d4.y, d4.z, d4.w};
    float res[8];

#pragma unroll
    for (int i = 0; i < 4; ++i) {
        float gx32 = (float)__dmul_rn(st, cpv[i]);
        float gy32 = (float)__dmul_rn(st, spv[i]);
        px_f32_chain(gx32, gy32, zc, dv[i], T, &res[2 * i]);
    }

    float4* o = reinterpret_cast<float4*>(out + (size_t)pix * 2);
    o[0] = make_float4(res[0], res[1], res[2], res[3]);
    o[1] = make_float4(res[4], res[5], res[6], res[7]);
}

extern "C" void kernel_launch(void* const* d_in, const int* in_sizes, int n_in,
                              void* d_out, int out_size, void* d_ws, size_t ws_size,
                              hipStream_t stream)
{
    const float* depth = (const float*)d_in[0];
    const float* trans = (const float*)d_in[1];
    float*       out   = (float*)d_out;
    double*      ws    = (double*)d_ws;

    const int total_pix = 4 * HGT * WID;   // 8,388,608
    const int threads   = total_pix / 4;   // 2,097,152
    const int blocks    = threads / 256;   // 8192

    if (ws_size >= WS_DOUBLES * sizeof(double)) {
        fill_tables_k<<<(WID + 255) / 256, 256, 0, stream>>>(ws);
        depth3d_k<<<blocks, 256, 0, stream>>>(depth, trans, ws, out);
    } else {
        depth3d_inline_k<<<blocks, 256, 0, stream>>>(depth, trans, out);
    }
}